// Round 16
// baseline (172.128 us; speedup 1.0000x reference)
//
#include <hip/hip_runtime.h>
#include <math.h>

#define BATCH 4
#define SEQ   4096
#define EMB   1024
#define HDIM  64
#define NSPLIT 4

typedef __attribute__((ext_vector_type(8))) short bf16x8;
typedef __attribute__((ext_vector_type(4))) float f32x4;
typedef __attribute__((ext_vector_type(4))) unsigned int u32x4;

#define MFMA16(a, b, c) __builtin_amdgcn_mfma_f32_16x16x32_bf16(a, b, c, 0, 0, 0)

__device__ __forceinline__ unsigned short f2bf(float f) {
  unsigned int u = __float_as_uint(f);
  u = (u + 0x7FFFu + ((u >> 16) & 1u)) >> 16;   // RNE
  return (unsigned short)u;
}

__device__ __forceinline__ float fexp2(float x) {  // 2^x, hw v_exp_f32
  float r;
  asm("v_exp_f32 %0, %1" : "=v"(r) : "v"(x));
  return r;
}

// ---- W pre-transpose: W[1024][64] f32 x3 -> Wt[192][1024] bf16 --------------
// Also zeroes the 128 pair-merge counters (runs first on the stream).
__global__ __launch_bounds__(256) void wt_kernel(
    const float* __restrict__ Wq, const float* __restrict__ Wk,
    const float* __restrict__ Wv, unsigned short* __restrict__ wt,
    int* __restrict__ cnt) {
  __shared__ float tile[64][65];
  const int bid = blockIdx.x;           // 48 = 3 matrices x 16 k-tiles
  const int m = bid >> 4, kt = bid & 15;
  const float* W = (m == 0) ? Wq : (m == 1) ? Wk : Wv;
  const int tid = threadIdx.x;
  if (bid == 0 && tid < 128) cnt[tid] = 0;       // reset merge counters
  {
    const int r = tid >> 2, c4 = tid & 3;
    const float* src = W + (size_t)(kt * 64 + r) * 64 + c4 * 16;
#pragma unroll
    for (int j = 0; j < 4; ++j) {
      float4 a = *(const float4*)(src + j * 4);
      tile[r][c4 * 16 + j * 4 + 0] = a.x;
      tile[r][c4 * 16 + j * 4 + 1] = a.y;
      tile[r][c4 * 16 + j * 4 + 2] = a.z;
      tile[r][c4 * 16 + j * 4 + 3] = a.w;
    }
  }
  __syncthreads();
  {
    const int col = tid >> 2, kq = tid & 3;
    unsigned short o[16];
#pragma unroll
    for (int j = 0; j < 16; ++j) o[j] = f2bf(tile[kq * 16 + j][col]);
    unsigned short* dst = wt + (size_t)(m * 64 + col) * 1024 + kt * 64 + kq * 16;
    *(bf16x8*)(dst)     = *(bf16x8*)&o[0];
    *(bf16x8*)(dst + 8) = *(bf16x8*)&o[8];
  }
}

// ---------------- QKV projection via MFMA (round-14 proven version) ---------
__global__ __launch_bounds__(256) void qkv_mfma_kernel(
    const float* __restrict__ x, const unsigned short* __restrict__ wt,
    unsigned short* __restrict__ qb, unsigned short* __restrict__ kb,
    unsigned short* __restrict__ vt) {
  __shared__ __align__(16) unsigned short xs[32 * 64];
  __shared__ __align__(16) unsigned short ws[192 * 64];
  const int tid  = threadIdx.x;
  const int lane = tid & 63, wid = tid >> 6;
  const int g = lane >> 4, p = lane & 15;
  const size_t row0 = (size_t)blockIdx.x * 32;

  const int sr = tid >> 3, sc = tid & 7;
  const float* xp = x + (row0 + sr) * EMB + sc * 8;

  f32x4 acc[2][3];
#pragma unroll
  for (int rt = 0; rt < 2; ++rt)
#pragma unroll
    for (int ct = 0; ct < 3; ++ct) acc[rt][ct] = (f32x4){0.f, 0.f, 0.f, 0.f};

  float4 rx[2];
  bf16x8 rw[6];
#pragma unroll
  for (int j = 0; j < 2; ++j) rx[j] = *(const float4*)(xp + j * 4);
#pragma unroll
  for (int it = 0; it < 6; ++it) {
    int i = tid + it * 256, col = i >> 3, cc = i & 7;
    rw[it] = *(const bf16x8*)(wt + (size_t)col * 1024 + cc * 8);
  }

  for (int kc = 0; kc < 16; ++kc) {
    __syncthreads();
#pragma unroll
    for (int j = 0; j < 2; ++j) {
      ushort4 h;
      h.x = f2bf(rx[j].x); h.y = f2bf(rx[j].y);
      h.z = f2bf(rx[j].z); h.w = f2bf(rx[j].w);
      *(ushort4*)((char*)xs + ((sr * 128 + sc * 16 + j * 8) ^ ((sr & 7) << 4))) = h;
    }
#pragma unroll
    for (int it = 0; it < 6; ++it) {
      int i = tid + it * 256, col = i >> 3, cc = i & 7;
      *(bf16x8*)((char*)ws + ((col * 128 + cc * 16) ^ ((col & 7) << 4))) = rw[it];
    }
    if (kc < 15) {
      const float* xpn = xp + (kc + 1) * 64;
#pragma unroll
      for (int j = 0; j < 2; ++j) rx[j] = *(const float4*)(xpn + j * 4);
#pragma unroll
      for (int it = 0; it < 6; ++it) {
        int i = tid + it * 256, col = i >> 3, cc = i & 7;
        rw[it] = *(const bf16x8*)(wt + (size_t)col * 1024 + (kc + 1) * 64 + cc * 8);
      }
    }
    __syncthreads();
#pragma unroll
    for (int ks = 0; ks < 2; ++ks) {
      bf16x8 af[2];
#pragma unroll
      for (int rt = 0; rt < 2; ++rt) {
        int row = rt * 16 + p;
        af[rt] = *(const bf16x8*)((char*)xs +
                 ((row * 128 + ks * 64 + g * 16) ^ ((row & 7) << 4)));
      }
#pragma unroll
      for (int ct = 0; ct < 3; ++ct) {
        int col = wid * 48 + ct * 16 + p;
        bf16x8 bfr = *(const bf16x8*)((char*)ws +
                     ((col * 128 + ks * 64 + g * 16) ^ ((col & 7) << 4)));
#pragma unroll
        for (int rt = 0; rt < 2; ++rt)
          acc[rt][ct] = MFMA16(af[rt], bfr, acc[rt][ct]);
      }
    }
  }

  const int b     = (int)(row0 >> 12);
  const int tbase = (int)(row0 & 4095);
  unsigned short* vtb = vt + (((size_t)b * 64 + (tbase >> 6)) * 64) * 64 + (tbase & 63);
#pragma unroll
  for (int rt = 0; rt < 2; ++rt)
#pragma unroll
    for (int ct = 0; ct < 3; ++ct) {
      const int c0  = wid * 48 + ct * 16;
      const int mtx = c0 >> 6;
      const int col = (c0 & 63) + p;
#pragma unroll
      for (int r = 0; r < 4; ++r) {
        const int row = rt * 16 + 4 * g + r;
        const float vf = acc[rt][ct][r];
        if (mtx == 0)      qb[(row0 + row) * HDIM + col] = f2bf(vf * 0.0450843714f);
        else if (mtx == 1) kb[(row0 + row) * HDIM + col] = f2bf(vf);
        else               vtb[(size_t)col * 64 + row]   = f2bf(vf);
      }
    }
}

// ---- one 64-key tile from swizzled LDS; cvt_pk + word-shuffle transpose ----
__device__ __forceinline__ void tile_body_lds(
    const unsigned short* __restrict__ sKb, const unsigned short* __restrict__ sVb,
    int qrel, bool diag,
    const bf16x8& qf0, const bf16x8& qf1,
    int p, int g, int cA0, int cA1, int srcA, int srcB, bool hi,
    float& m, float& l, f32x4 (&o)[4]) {
  f32x4 sc4[4];
#pragma unroll
  for (int t = 0; t < 4; ++t) {
    const int row = 16 * t + p;
    bf16x8 a0 = *(const bf16x8*)((const char*)sKb + row * 128 + cA0);
    bf16x8 a1 = *(const bf16x8*)((const char*)sKb + row * 128 + cA1);
    f32x4 a = (f32x4){0.f, 0.f, 0.f, 0.f};
    a = MFMA16(a0, qf0, a);
    a = MFMA16(a1, qf1, a);
    sc4[t] = a;
  }
  if (diag) {
#pragma unroll
    for (int t = 0; t < 4; ++t)
#pragma unroll
      for (int r = 0; r < 4; ++r)
        if (16 * t + 4 * g + r > qrel) sc4[t][r] = -1e30f;
  }
  float tm = -3e38f;
#pragma unroll
  for (int t = 0; t < 4; ++t)
#pragma unroll
    for (int r = 0; r < 4; ++r) tm = fmaxf(tm, sc4[t][r]);
  tm = fmaxf(tm, __shfl_xor(tm, 16));
  tm = fmaxf(tm, __shfl_xor(tm, 32));
  if (__any(tm > m + 11.5f)) {               // defer-max (T13)
    float mn = fmaxf(m, tm);
    float c = fexp2(m - mn);
    l *= c;
#pragma unroll
    for (int mi = 0; mi < 4; ++mi) o[mi] *= c;
    m = mn;
  }
  float psum = 0.f;
#pragma unroll
  for (int t = 0; t < 4; ++t)
#pragma unroll
    for (int r = 0; r < 4; ++r) {
      float pv = fexp2(sc4[t][r] - m);
      sc4[t][r] = pv;
      psum += pv;
    }
  l += psum;
  unsigned int pk[4][2];
#pragma unroll
  for (int t = 0; t < 4; ++t) {
    asm("v_cvt_pk_bf16_f32 %0, %1, %2"
        : "=v"(pk[t][0]) : "v"(sc4[t][0]), "v"(sc4[t][1]));
    asm("v_cvt_pk_bf16_f32 %0, %1, %2"
        : "=v"(pk[t][1]) : "v"(sc4[t][2]), "v"(sc4[t][3]));
  }
  u32x4 wb0, wb1;
#pragma unroll
  for (int h2 = 0; h2 < 2; ++h2) {
    const int src = h2 ? srcB : srcA;
    unsigned c0 = (unsigned)__shfl((int)pk[0][0], src);
    unsigned c1 = (unsigned)__shfl((int)pk[1][0], src);
    wb0[2 * h2 + 0] = hi ? c1 : c0;
    unsigned d0 = (unsigned)__shfl((int)pk[0][1], src);
    unsigned d1 = (unsigned)__shfl((int)pk[1][1], src);
    wb0[2 * h2 + 1] = hi ? d1 : d0;
    unsigned e0 = (unsigned)__shfl((int)pk[2][0], src);
    unsigned e1 = (unsigned)__shfl((int)pk[3][0], src);
    wb1[2 * h2 + 0] = hi ? e1 : e0;
    unsigned f0 = (unsigned)__shfl((int)pk[2][1], src);
    unsigned f1 = (unsigned)__shfl((int)pk[3][1], src);
    wb1[2 * h2 + 1] = hi ? f1 : f0;
  }
  bf16x8 b0 = __builtin_bit_cast(bf16x8, wb0);
  bf16x8 b1 = __builtin_bit_cast(bf16x8, wb1);
#pragma unroll
  for (int mi = 0; mi < 4; ++mi) {
    const int rowv = 16 * mi + p;
    bf16x8 va0 = *(const bf16x8*)((const char*)sVb + rowv * 128 + cA0);
    bf16x8 va1 = *(const bf16x8*)((const char*)sVb + rowv * 128 + cA1);
    o[mi] = MFMA16(va0, b0, o[mi]);
    o[mi] = MFMA16(va1, b1, o[mi]);
  }
}

__device__ __forceinline__ void item_map(int g_it, int j, int& kt, bool& isA, bool& diag) {
  if (g_it <= j) { isA = true;  kt = g_it;         diag = (g_it == j); }
  else           { isA = false; kt = g_it - j - 1; diag = (kt == 63 - j); }
}

// ---- flash attention: LDS-staged K/V shared by 4 waves + FUSED merge -------
// After writing its partials, each split-block bumps a device-scope counter
// for its (b,j) pair; the 4th arriver merges all 8 query-groups and writes
// the normalized output (split-K fixup pattern; deterministic values).
__global__ __launch_bounds__(256) void attn_partial_kernel(
    const unsigned short* __restrict__ qb, const unsigned short* __restrict__ kbm,
    const unsigned short* __restrict__ vt, float* __restrict__ pw,
    int* __restrict__ cnt, float* __restrict__ out) {
  __shared__ __align__(16) unsigned short sK[2][4096];
  __shared__ __align__(16) unsigned short sV[2][4096];
  __shared__ int lastf;
  const int tid = threadIdx.x;
  const int wid = tid >> 6, lane = tid & 63;
  const int g = lane >> 4, p = lane & 15;
  const int bid = blockIdx.x;
  const int sp = bid & 3, j = (bid >> 2) & 31, b = bid >> 7;
  const int jB = 63 - j;
  const int tq0A = j * 64 + 16 * wid;
  const int tq0B = jB * 64 + 16 * wid;

  const char* kbase = (const char*)(kbm + (size_t)b * SEQ * HDIM);
  const char* vbase = (const char*)(vt  + (size_t)b * SEQ * HDIM);

  const unsigned short* qrowA = qb + ((size_t)b * SEQ + tq0A + p) * HDIM;
  const bf16x8 qfA0 = *(const bf16x8*)(qrowA + 8 * g);
  const bf16x8 qfA1 = *(const bf16x8*)(qrowA + 32 + 8 * g);
  const unsigned short* qrowB = qb + ((size_t)b * SEQ + tq0B + p) * HDIM;
  const bf16x8 qfB0 = *(const bf16x8*)(qrowB + 8 * g);
  const bf16x8 qfB1 = *(const bf16x8*)(qrowB + 32 + 8 * g);

  const int slot0 = tid * 16, slot1 = slot0 + 4096;
  const int r0 = slot0 >> 7, koff0 = r0 * 128 + ((slot0 & 127) ^ ((r0 & 7) << 4));
  const int r1 = slot1 >> 7, koff1 = r1 * 128 + ((slot1 & 127) ^ ((r1 & 7) << 4));

  const int swz = (p & 7) << 4;
  const int cA0 = (16 * g) ^ swz, cA1 = (64 + 16 * g) ^ swz;

  const int srcA = (g & 1) * 32 + p;
  const int srcB = srcA + 16;
  const bool hi = (g >> 1) != 0;

  float mA = -1e30f, lA = 0.f, mB = -1e30f, lB = 0.f;
  f32x4 oA[4], oB[4];
#pragma unroll
  for (int mi = 0; mi < 4; ++mi) {
    oA[mi] = (f32x4){0.f, 0.f, 0.f, 0.f};
    oB[mi] = (f32x4){0.f, 0.f, 0.f, 0.f};
  }

  const int cntN = (65 - sp + NSPLIT - 1) / NSPLIT;   // 16 or 17

  bf16x8 rk0, rk1, rv0, rv1;
  {
    int kt; bool isA, diag;
    item_map(sp, j, kt, isA, diag);
    const char* kk = kbase + (size_t)kt * 8192;
    const char* vv = vbase + (size_t)kt * 8192;
    rk0 = *(const bf16x8*)(kk + koff0); rk1 = *(const bf16x8*)(kk + koff1);
    rv0 = *(const bf16x8*)(vv + koff0); rv1 = *(const bf16x8*)(vv + koff1);
  }

  for (int ii = 0; ii < cntN; ++ii) {
    const int buf = ii & 1;
    __syncthreads();
    *(bf16x8*)((char*)sK[buf] + slot0) = rk0;
    *(bf16x8*)((char*)sK[buf] + slot1) = rk1;
    *(bf16x8*)((char*)sV[buf] + slot0) = rv0;
    *(bf16x8*)((char*)sV[buf] + slot1) = rv1;
    if (ii + 1 < cntN) {                  // T14 issue-early
      int kt; bool isA, diag;
      item_map(sp + (ii + 1) * NSPLIT, j, kt, isA, diag);
      const char* kk = kbase + (size_t)kt * 8192;
      const char* vv = vbase + (size_t)kt * 8192;
      rk0 = *(const bf16x8*)(kk + koff0); rk1 = *(const bf16x8*)(kk + koff1);
      rv0 = *(const bf16x8*)(vv + koff0); rv1 = *(const bf16x8*)(vv + koff1);
    }
    __syncthreads();
    int kt; bool isA, diag;
    item_map(sp + ii * NSPLIT, j, kt, isA, diag);
    if (isA) {
      tile_body_lds(sK[buf], sV[buf], tq0A + p - kt * 64, diag, qfA0, qfA1,
                    p, g, cA0, cA1, srcA, srcB, hi, mA, lA, oA);
    } else {
      tile_body_lds(sK[buf], sV[buf], tq0B + p - kt * 64, diag, qfB0, qfB1,
                    p, g, cA0, cA1, srcA, srcB, hi, mB, lB, oB);
    }
  }

  lA += __shfl_xor(lA, 16); lA += __shfl_xor(lA, 32);
  lB += __shfl_xor(lB, 16); lB += __shfl_xor(lB, 32);

  {
    const int grpA = j * 4 + wid;
    float* pp = pw + ((size_t)(b * 256 + grpA) * NSPLIT + sp) * 1056;
#pragma unroll
    for (int mi = 0; mi < 4; ++mi)
      *(f32x4*)(pp + p * 64 + 16 * mi + 4 * g) = oA[mi];
    if (g == 0) { pp[1024 + p] = mA; pp[1040 + p] = lA; }
  }
  {
    const int grpB = jB * 4 + wid;
    float* pp = pw + ((size_t)(b * 256 + grpB) * NSPLIT + sp) * 1056;
#pragma unroll
    for (int mi = 0; mi < 4; ++mi)
      *(f32x4*)(pp + p * 64 + 16 * mi + 4 * g) = oB[mi];
    if (g == 0) { pp[1024 + p] = mB; pp[1040 + p] = lB; }
  }

  // ---- fused split-K fixup: last arriver of the 4 sp-blocks merges --------
  __threadfence();                        // release: partials -> device scope
  __syncthreads();
  if (tid == 0) lastf = (atomicAdd(&cnt[b * 32 + j], 1) == 3);
  __syncthreads();
  if (lastf) {
    __threadfence();                      // acquire
    const int q = tid & 15, db = tid >> 4;
#pragma unroll
    for (int gi = 0; gi < 8; ++gi) {
      const int grp = (gi < 4) ? (j * 4 + gi) : (jB * 4 + (gi - 4));
      const float* pp = pw + ((size_t)(b * 256 + grp) * NSPLIT) * 1056;
      float ms[NSPLIT], ls[NSPLIT];
      float mm = -3e38f;
#pragma unroll
      for (int s = 0; s < NSPLIT; ++s) {
        ms[s] = pp[s * 1056 + 1024 + q];
        ls[s] = pp[s * 1056 + 1040 + q];
        mm = fmaxf(mm, ms[s]);
      }
      float L = 0.f, a0 = 0.f, a1 = 0.f, a2 = 0.f, a3 = 0.f;
#pragma unroll
      for (int s = 0; s < NSPLIT; ++s) {
        float sc = fexp2(ms[s] - mm);
        L += ls[s] * sc;
        float4 v = *(const float4*)(pp + s * 1056 + q * 64 + 4 * db);
        a0 += v.x * sc; a1 += v.y * sc; a2 += v.z * sc; a3 += v.w * sc;
      }
      const float inv = 1.f / L;
      float* op = out + ((size_t)b * SEQ + grp * 16 + q) * HDIM + 4 * db;
      op[0] = a0 * inv; op[1] = a1 * inv; op[2] = a2 * inv; op[3] = a3 * inv;
    }
  }
}

extern "C" void kernel_launch(void* const* d_in, const int* in_sizes, int n_in,
                              void* d_out, int out_size, void* d_ws, size_t ws_size,
                              hipStream_t stream) {
  const float* x  = (const float*)d_in[0];
  const float* Wq = (const float*)d_in[1];
  const float* Wk = (const float*)d_in[2];
  const float* Wv = (const float*)d_in[3];
  float* outp = (float*)d_out;

  const size_t rows = (size_t)BATCH * SEQ;        // 16384
  unsigned short* qbf = (unsigned short*)d_ws;
  unsigned short* kbf = qbf + rows * HDIM;
  unsigned short* vtb = kbf + rows * HDIM;
  unsigned short* wt  = vtb + rows * HDIM;        // 192*1024 bf16
  float* pw = (float*)(wt + 192 * 1024);          // 4096 partials x 1056 f32
  int* cnt  = (int*)(pw + (size_t)4096 * 1056);   // 128 pair counters

  wt_kernel<<<dim3(48), dim3(256), 0, stream>>>(Wq, Wk, Wv, wt, cnt);
  qkv_mfma_kernel<<<dim3((unsigned)(rows / 32)), dim3(256), 0, stream>>>(x, wt, qbf, kbf, vtb);
  attn_partial_kernel<<<dim3(512), dim3(256), 0, stream>>>(qbf, kbf, vtb, pw, cnt, outp);
}

// Round 17
// 61.351 us; speedup vs baseline: 2.8056x; 2.8056x over previous
//
#include <hip/hip_runtime.h>
#include <math.h>

#define BATCH 4
#define SEQ   4096
#define EMB   1024
#define HDIM  64
#define NSPLIT 4

typedef __attribute__((ext_vector_type(8))) short bf16x8;
typedef __attribute__((ext_vector_type(4))) float f32x4;
typedef __attribute__((ext_vector_type(4))) unsigned int u32x4;

#define MFMA16(a, b, c) __builtin_amdgcn_mfma_f32_16x16x32_bf16(a, b, c, 0, 0, 0)

__device__ __forceinline__ unsigned short f2bf(float f) {
  unsigned int u = __float_as_uint(f);
  u = (u + 0x7FFFu + ((u >> 16) & 1u)) >> 16;   // RNE
  return (unsigned short)u;
}

__device__ __forceinline__ float fexp2(float x) {  // 2^x, hw v_exp_f32
  float r;
  asm("v_exp_f32 %0, %1" : "=v"(r) : "v"(x));
  return r;
}

// ---- W pre-transpose: W[1024][64] f32 x3 -> Wt[192][1024] bf16 --------------
__global__ __launch_bounds__(256) void wt_kernel(
    const float* __restrict__ Wq, const float* __restrict__ Wk,
    const float* __restrict__ Wv, unsigned short* __restrict__ wt) {
  __shared__ float tile[64][65];
  const int bid = blockIdx.x;           // 48 = 3 matrices x 16 k-tiles
  const int m = bid >> 4, kt = bid & 15;
  const float* W = (m == 0) ? Wq : (m == 1) ? Wk : Wv;
  const int tid = threadIdx.x;
  {
    const int r = tid >> 2, c4 = tid & 3;
    const float* src = W + (size_t)(kt * 64 + r) * 64 + c4 * 16;
#pragma unroll
    for (int j = 0; j < 4; ++j) {
      float4 a = *(const float4*)(src + j * 4);
      tile[r][c4 * 16 + j * 4 + 0] = a.x;
      tile[r][c4 * 16 + j * 4 + 1] = a.y;
      tile[r][c4 * 16 + j * 4 + 2] = a.z;
      tile[r][c4 * 16 + j * 4 + 3] = a.w;
    }
  }
  __syncthreads();
  {
    const int col = tid >> 2, kq = tid & 3;
    unsigned short o[16];
#pragma unroll
    for (int j = 0; j < 16; ++j) o[j] = f2bf(tile[kq * 16 + j][col]);
    unsigned short* dst = wt + (size_t)(m * 64 + col) * 1024 + kt * 64 + kq * 16;
    *(bf16x8*)(dst)     = *(bf16x8*)&o[0];
    *(bf16x8*)(dst + 8) = *(bf16x8*)&o[8];
  }
}

// ---------------- QKV projection via MFMA (round-14 proven version) ---------
__global__ __launch_bounds__(256) void qkv_mfma_kernel(
    const float* __restrict__ x, const unsigned short* __restrict__ wt,
    unsigned short* __restrict__ qb, unsigned short* __restrict__ kb,
    unsigned short* __restrict__ vt) {
  __shared__ __align__(16) unsigned short xs[32 * 64];
  __shared__ __align__(16) unsigned short ws[192 * 64];
  const int tid  = threadIdx.x;
  const int lane = tid & 63, wid = tid >> 6;
  const int g = lane >> 4, p = lane & 15;
  const size_t row0 = (size_t)blockIdx.x * 32;

  const int sr = tid >> 3, sc = tid & 7;
  const float* xp = x + (row0 + sr) * EMB + sc * 8;

  f32x4 acc[2][3];
#pragma unroll
  for (int rt = 0; rt < 2; ++rt)
#pragma unroll
    for (int ct = 0; ct < 3; ++ct) acc[rt][ct] = (f32x4){0.f, 0.f, 0.f, 0.f};

  float4 rx[2];
  bf16x8 rw[6];
#pragma unroll
  for (int j = 0; j < 2; ++j) rx[j] = *(const float4*)(xp + j * 4);
#pragma unroll
  for (int it = 0; it < 6; ++it) {
    int i = tid + it * 256, col = i >> 3, cc = i & 7;
    rw[it] = *(const bf16x8*)(wt + (size_t)col * 1024 + cc * 8);
  }

  for (int kc = 0; kc < 16; ++kc) {
    __syncthreads();
#pragma unroll
    for (int j = 0; j < 2; ++j) {
      ushort4 h;
      h.x = f2bf(rx[j].x); h.y = f2bf(rx[j].y);
      h.z = f2bf(rx[j].z); h.w = f2bf(rx[j].w);
      *(ushort4*)((char*)xs + ((sr * 128 + sc * 16 + j * 8) ^ ((sr & 7) << 4))) = h;
    }
#pragma unroll
    for (int it = 0; it < 6; ++it) {
      int i = tid + it * 256, col = i >> 3, cc = i & 7;
      *(bf16x8*)((char*)ws + ((col * 128 + cc * 16) ^ ((col & 7) << 4))) = rw[it];
    }
    if (kc < 15) {
      const float* xpn = xp + (kc + 1) * 64;
#pragma unroll
      for (int j = 0; j < 2; ++j) rx[j] = *(const float4*)(xpn + j * 4);
#pragma unroll
      for (int it = 0; it < 6; ++it) {
        int i = tid + it * 256, col = i >> 3, cc = i & 7;
        rw[it] = *(const bf16x8*)(wt + (size_t)col * 1024 + (kc + 1) * 64 + cc * 8);
      }
    }
    __syncthreads();
#pragma unroll
    for (int ks = 0; ks < 2; ++ks) {
      bf16x8 af[2];
#pragma unroll
      for (int rt = 0; rt < 2; ++rt) {
        int row = rt * 16 + p;
        af[rt] = *(const bf16x8*)((char*)xs +
                 ((row * 128 + ks * 64 + g * 16) ^ ((row & 7) << 4)));
      }
#pragma unroll
      for (int ct = 0; ct < 3; ++ct) {
        int col = wid * 48 + ct * 16 + p;
        bf16x8 bfr = *(const bf16x8*)((char*)ws +
                     ((col * 128 + ks * 64 + g * 16) ^ ((col & 7) << 4)));
#pragma unroll
        for (int rt = 0; rt < 2; ++rt)
          acc[rt][ct] = MFMA16(af[rt], bfr, acc[rt][ct]);
      }
    }
  }

  const int b     = (int)(row0 >> 12);
  const int tbase = (int)(row0 & 4095);
  unsigned short* vtb = vt + (((size_t)b * 64 + (tbase >> 6)) * 64) * 64 + (tbase & 63);
#pragma unroll
  for (int rt = 0; rt < 2; ++rt)
#pragma unroll
    for (int ct = 0; ct < 3; ++ct) {
      const int c0  = wid * 48 + ct * 16;
      const int mtx = c0 >> 6;
      const int col = (c0 & 63) + p;
#pragma unroll
      for (int r = 0; r < 4; ++r) {
        const int row = rt * 16 + 4 * g + r;
        const float vf = acc[rt][ct][r];
        if (mtx == 0)      qb[(row0 + row) * HDIM + col] = f2bf(vf * 0.0450843714f);
        else if (mtx == 1) kb[(row0 + row) * HDIM + col] = f2bf(vf);
        else               vtb[(size_t)col * 64 + row]   = f2bf(vf);
      }
    }
}

// ---- one 64-key tile from swizzled LDS; cvt_pk + word-shuffle transpose ----
__device__ __forceinline__ void tile_body_lds(
    const unsigned short* __restrict__ sKb, const unsigned short* __restrict__ sVb,
    int qrel, bool diag,
    const bf16x8& qf0, const bf16x8& qf1,
    int p, int g, int cA0, int cA1, int srcA, int srcB, bool hi,
    float& m, float& l, f32x4 (&o)[4]) {
  f32x4 sc4[4];
#pragma unroll
  for (int t = 0; t < 4; ++t) {
    const int row = 16 * t + p;
    bf16x8 a0 = *(const bf16x8*)((const char*)sKb + row * 128 + cA0);
    bf16x8 a1 = *(const bf16x8*)((const char*)sKb + row * 128 + cA1);
    f32x4 a = (f32x4){0.f, 0.f, 0.f, 0.f};
    a = MFMA16(a0, qf0, a);
    a = MFMA16(a1, qf1, a);
    sc4[t] = a;
  }
  if (diag) {
#pragma unroll
    for (int t = 0; t < 4; ++t)
#pragma unroll
      for (int r = 0; r < 4; ++r)
        if (16 * t + 4 * g + r > qrel) sc4[t][r] = -1e30f;
  }
  float tm = -3e38f;
#pragma unroll
  for (int t = 0; t < 4; ++t)
#pragma unroll
    for (int r = 0; r < 4; ++r) tm = fmaxf(tm, sc4[t][r]);
  tm = fmaxf(tm, __shfl_xor(tm, 16));
  tm = fmaxf(tm, __shfl_xor(tm, 32));
  if (__any(tm > m + 11.5f)) {               // defer-max (T13)
    float mn = fmaxf(m, tm);
    float c = fexp2(m - mn);
    l *= c;
#pragma unroll
    for (int mi = 0; mi < 4; ++mi) o[mi] *= c;
    m = mn;
  }
  float psum = 0.f;
#pragma unroll
  for (int t = 0; t < 4; ++t)
#pragma unroll
    for (int r = 0; r < 4; ++r) {
      float pv = fexp2(sc4[t][r] - m);
      sc4[t][r] = pv;
      psum += pv;
    }
  l += psum;
  unsigned int pk[4][2];
#pragma unroll
  for (int t = 0; t < 4; ++t) {
    asm("v_cvt_pk_bf16_f32 %0, %1, %2"
        : "=v"(pk[t][0]) : "v"(sc4[t][0]), "v"(sc4[t][1]));
    asm("v_cvt_pk_bf16_f32 %0, %1, %2"
        : "=v"(pk[t][1]) : "v"(sc4[t][2]), "v"(sc4[t][3]));
  }
  u32x4 wb0, wb1;
#pragma unroll
  for (int h2 = 0; h2 < 2; ++h2) {
    const int src = h2 ? srcB : srcA;
    unsigned c0 = (unsigned)__shfl((int)pk[0][0], src);
    unsigned c1 = (unsigned)__shfl((int)pk[1][0], src);
    wb0[2 * h2 + 0] = hi ? c1 : c0;
    unsigned d0 = (unsigned)__shfl((int)pk[0][1], src);
    unsigned d1 = (unsigned)__shfl((int)pk[1][1], src);
    wb0[2 * h2 + 1] = hi ? d1 : d0;
    unsigned e0 = (unsigned)__shfl((int)pk[2][0], src);
    unsigned e1 = (unsigned)__shfl((int)pk[3][0], src);
    wb1[2 * h2 + 0] = hi ? e1 : e0;
    unsigned f0 = (unsigned)__shfl((int)pk[2][1], src);
    unsigned f1 = (unsigned)__shfl((int)pk[3][1], src);
    wb1[2 * h2 + 1] = hi ? f1 : f0;
  }
  bf16x8 b0 = __builtin_bit_cast(bf16x8, wb0);
  bf16x8 b1 = __builtin_bit_cast(bf16x8, wb1);
#pragma unroll
  for (int mi = 0; mi < 4; ++mi) {
    const int rowv = 16 * mi + p;
    bf16x8 va0 = *(const bf16x8*)((const char*)sVb + rowv * 128 + cA0);
    bf16x8 va1 = *(const bf16x8*)((const char*)sVb + rowv * 128 + cA1);
    o[mi] = MFMA16(va0, b0, o[mi]);
    o[mi] = MFMA16(va1, b1, o[mi]);
  }
}

__device__ __forceinline__ void item_map(int g_it, int j, int& kt, bool& isA, bool& diag) {
  if (g_it <= j) { isA = true;  kt = g_it;         diag = (g_it == j); }
  else           { isA = false; kt = g_it - j - 1; diag = (kt == 63 - j); }
}

// ---- flash attention stage 1: LDS-staged K/V, ONE barrier per item ---------
// Canonical double-buffer: iter ii writes item ii+1 into buf^1 while
// computing item ii from buf; single barrier at loop end separates the
// write->read of buf^1 and the read->overwrite of buf. Halves barrier count.
__global__ __launch_bounds__(256) void attn_partial_kernel(
    const unsigned short* __restrict__ qb, const unsigned short* __restrict__ kbm,
    const unsigned short* __restrict__ vt, float* __restrict__ pw) {
  __shared__ __align__(16) unsigned short sK[2][4096];
  __shared__ __align__(16) unsigned short sV[2][4096];
  const int tid = threadIdx.x;
  const int wid = tid >> 6, lane = tid & 63;
  const int g = lane >> 4, p = lane & 15;
  const int bid = blockIdx.x;
  const int sp = bid & 3, j = (bid >> 2) & 31, b = bid >> 7;
  const int jB = 63 - j;
  const int tq0A = j * 64 + 16 * wid;
  const int tq0B = jB * 64 + 16 * wid;

  const char* kbase = (const char*)(kbm + (size_t)b * SEQ * HDIM);
  const char* vbase = (const char*)(vt  + (size_t)b * SEQ * HDIM);

  const unsigned short* qrowA = qb + ((size_t)b * SEQ + tq0A + p) * HDIM;
  const bf16x8 qfA0 = *(const bf16x8*)(qrowA + 8 * g);
  const bf16x8 qfA1 = *(const bf16x8*)(qrowA + 32 + 8 * g);
  const unsigned short* qrowB = qb + ((size_t)b * SEQ + tq0B + p) * HDIM;
  const bf16x8 qfB0 = *(const bf16x8*)(qrowB + 8 * g);
  const bf16x8 qfB1 = *(const bf16x8*)(qrowB + 32 + 8 * g);

  const int slot0 = tid * 16, slot1 = slot0 + 4096;
  const int r0 = slot0 >> 7, koff0 = r0 * 128 + ((slot0 & 127) ^ ((r0 & 7) << 4));
  const int r1 = slot1 >> 7, koff1 = r1 * 128 + ((slot1 & 127) ^ ((r1 & 7) << 4));

  const int swz = (p & 7) << 4;
  const int cA0 = (16 * g) ^ swz, cA1 = (64 + 16 * g) ^ swz;

  const int srcA = (g & 1) * 32 + p;
  const int srcB = srcA + 16;
  const bool hi = (g >> 1) != 0;

  float mA = -1e30f, lA = 0.f, mB = -1e30f, lB = 0.f;
  f32x4 oA[4], oB[4];
#pragma unroll
  for (int mi = 0; mi < 4; ++mi) {
    oA[mi] = (f32x4){0.f, 0.f, 0.f, 0.f};
    oB[mi] = (f32x4){0.f, 0.f, 0.f, 0.f};
  }

  const int cnt = (65 - sp + NSPLIT - 1) / NSPLIT;   // 16 or 17

  bf16x8 rk0, rk1, rv0, rv1;
  // prologue: load item 0, write buf0, preload item 1
  {
    int kt; bool isA, diag;
    item_map(sp, j, kt, isA, diag);
    const char* kk = kbase + (size_t)kt * 8192;
    const char* vv = vbase + (size_t)kt * 8192;
    rk0 = *(const bf16x8*)(kk + koff0); rk1 = *(const bf16x8*)(kk + koff1);
    rv0 = *(const bf16x8*)(vv + koff0); rv1 = *(const bf16x8*)(vv + koff1);
  }
  *(bf16x8*)((char*)sK[0] + slot0) = rk0;
  *(bf16x8*)((char*)sK[0] + slot1) = rk1;
  *(bf16x8*)((char*)sV[0] + slot0) = rv0;
  *(bf16x8*)((char*)sV[0] + slot1) = rv1;
  if (cnt > 1) {
    int kt; bool isA, diag;
    item_map(sp + NSPLIT, j, kt, isA, diag);
    const char* kk = kbase + (size_t)kt * 8192;
    const char* vv = vbase + (size_t)kt * 8192;
    rk0 = *(const bf16x8*)(kk + koff0); rk1 = *(const bf16x8*)(kk + koff1);
    rv0 = *(const bf16x8*)(vv + koff0); rv1 = *(const bf16x8*)(vv + koff1);
  }
  __syncthreads();

  for (int ii = 0; ii < cnt; ++ii) {
    const int buf = ii & 1;
    if (ii + 1 < cnt) {                   // write item ii+1 into other buf
      const int nb = buf ^ 1;
      *(bf16x8*)((char*)sK[nb] + slot0) = rk0;
      *(bf16x8*)((char*)sK[nb] + slot1) = rk1;
      *(bf16x8*)((char*)sV[nb] + slot0) = rv0;
      *(bf16x8*)((char*)sV[nb] + slot1) = rv1;
    }
    if (ii + 2 < cnt) {                   // T14 issue-early: load item ii+2
      int kt; bool isA, diag;
      item_map(sp + (ii + 2) * NSPLIT, j, kt, isA, diag);
      const char* kk = kbase + (size_t)kt * 8192;
      const char* vv = vbase + (size_t)kt * 8192;
      rk0 = *(const bf16x8*)(kk + koff0); rk1 = *(const bf16x8*)(kk + koff1);
      rv0 = *(const bf16x8*)(vv + koff0); rv1 = *(const bf16x8*)(vv + koff1);
    }
    int kt; bool isA, diag;
    item_map(sp + ii * NSPLIT, j, kt, isA, diag);
    if (isA) {
      tile_body_lds(sK[buf], sV[buf], tq0A + p - kt * 64, diag, qfA0, qfA1,
                    p, g, cA0, cA1, srcA, srcB, hi, mA, lA, oA);
    } else {
      tile_body_lds(sK[buf], sV[buf], tq0B + p - kt * 64, diag, qfB0, qfB1,
                    p, g, cA0, cA1, srcA, srcB, hi, mB, lB, oB);
    }
    __syncthreads();                      // single barrier per item
  }

  lA += __shfl_xor(lA, 16); lA += __shfl_xor(lA, 32);
  lB += __shfl_xor(lB, 16); lB += __shfl_xor(lB, 32);

  {
    const int grpA = j * 4 + wid;
    float* pp = pw + ((size_t)(b * 256 + grpA) * NSPLIT + sp) * 1056;
#pragma unroll
    for (int mi = 0; mi < 4; ++mi)
      *(f32x4*)(pp + p * 64 + 16 * mi + 4 * g) = oA[mi];
    if (g == 0) { pp[1024 + p] = mA; pp[1040 + p] = lA; }
  }
  {
    const int grpB = jB * 4 + wid;
    float* pp = pw + ((size_t)(b * 256 + grpB) * NSPLIT + sp) * 1056;
#pragma unroll
    for (int mi = 0; mi < 4; ++mi)
      *(f32x4*)(pp + p * 64 + 16 * mi + 4 * g) = oB[mi];
    if (g == 0) { pp[1024 + p] = mB; pp[1040 + p] = lB; }
  }
}

// ---- stage 2: merge NSPLIT partials per (batch, 16-query group), normalize -
__global__ __launch_bounds__(256) void attn_merge_kernel(
    const float* __restrict__ pw, float* __restrict__ out) {
  const int bid = blockIdx.x;                   // b*256 + grp
  const int b = bid >> 8, grp = bid & 255;
  const int q = threadIdx.x & 15, db = threadIdx.x >> 4;
  const float* pp = pw + (size_t)bid * NSPLIT * 1056;
  float ms[NSPLIT], ls[NSPLIT];
  float mm = -3e38f;
#pragma unroll
  for (int s = 0; s < NSPLIT; ++s) {
    ms[s] = pp[s * 1056 + 1024 + q];
    ls[s] = pp[s * 1056 + 1040 + q];
    mm = fmaxf(mm, ms[s]);
  }
  float L = 0.f, a0 = 0.f, a1 = 0.f, a2 = 0.f, a3 = 0.f;
#pragma unroll
  for (int s = 0; s < NSPLIT; ++s) {
    float sc = fexp2(ms[s] - mm);
    L += ls[s] * sc;
    float4 v = *(const float4*)(pp + s * 1056 + q * 64 + 4 * db);
    a0 += v.x * sc; a1 += v.y * sc; a2 += v.z * sc; a3 += v.w * sc;
  }
  const float inv = 1.f / L;
  float* op = out + ((size_t)b * SEQ + grp * 16 + q) * HDIM + 4 * db;
  op[0] = a0 * inv; op[1] = a1 * inv; op[2] = a2 * inv; op[3] = a3 * inv;
}

extern "C" void kernel_launch(void* const* d_in, const int* in_sizes, int n_in,
                              void* d_out, int out_size, void* d_ws, size_t ws_size,
                              hipStream_t stream) {
  const float* x  = (const float*)d_in[0];
  const float* Wq = (const float*)d_in[1];
  const float* Wk = (const float*)d_in[2];
  const float* Wv = (const float*)d_in[3];
  float* outp = (float*)d_out;

  const size_t rows = (size_t)BATCH * SEQ;        // 16384
  unsigned short* qbf = (unsigned short*)d_ws;
  unsigned short* kbf = qbf + rows * HDIM;
  unsigned short* vtb = kbf + rows * HDIM;
  unsigned short* wt  = vtb + rows * HDIM;        // 192*1024 bf16
  float* pw = (float*)(wt + 192 * 1024);          // 4096 partials x 1056 f32

  wt_kernel<<<dim3(48), dim3(256), 0, stream>>>(Wq, Wk, Wv, wt);
  qkv_mfma_kernel<<<dim3((unsigned)(rows / 32)), dim3(256), 0, stream>>>(x, wt, qbf, kbf, vtb);
  attn_partial_kernel<<<dim3(512), dim3(256), 0, stream>>>(qbf, kbf, vtb, pw);
  attn_merge_kernel<<<dim3(1024), dim3(256), 0, stream>>>(pw, outp);
}

// Round 18
// 58.996 us; speedup vs baseline: 2.9176x; 1.0399x over previous
//
#include <hip/hip_runtime.h>
#include <math.h>

#define BATCH 4
#define SEQ   4096
#define EMB   1024
#define HDIM  64
#define NSPLIT 4

typedef __attribute__((ext_vector_type(8))) short bf16x8;
typedef __attribute__((ext_vector_type(4))) float f32x4;
typedef __attribute__((ext_vector_type(4))) unsigned int u32x4;

#define MFMA16(a, b, c) __builtin_amdgcn_mfma_f32_16x16x32_bf16(a, b, c, 0, 0, 0)

__device__ __forceinline__ unsigned short f2bf(float f) {
  unsigned int u = __float_as_uint(f);
  u = (u + 0x7FFFu + ((u >> 16) & 1u)) >> 16;   // RNE
  return (unsigned short)u;
}

__device__ __forceinline__ float fexp2(float x) {  // 2^x, hw v_exp_f32
  float r;
  asm("v_exp_f32 %0, %1" : "=v"(r) : "v"(x));
  return r;
}

// ---- W pre-transpose: W[1024][64] f32 x3 -> Wt[192][1024] bf16 --------------
__global__ __launch_bounds__(256) void wt_kernel(
    const float* __restrict__ Wq, const float* __restrict__ Wk,
    const float* __restrict__ Wv, unsigned short* __restrict__ wt) {
  __shared__ float tile[64][65];
  const int bid = blockIdx.x;           // 48 = 3 matrices x 16 k-tiles
  const int m = bid >> 4, kt = bid & 15;
  const float* W = (m == 0) ? Wq : (m == 1) ? Wk : Wv;
  const int tid = threadIdx.x;
  {
    const int r = tid >> 2, c4 = tid & 3;
    const float* src = W + (size_t)(kt * 64 + r) * 64 + c4 * 16;
#pragma unroll
    for (int j = 0; j < 4; ++j) {
      float4 a = *(const float4*)(src + j * 4);
      tile[r][c4 * 16 + j * 4 + 0] = a.x;
      tile[r][c4 * 16 + j * 4 + 1] = a.y;
      tile[r][c4 * 16 + j * 4 + 2] = a.z;
      tile[r][c4 * 16 + j * 4 + 3] = a.w;
    }
  }
  __syncthreads();
  {
    const int col = tid >> 2, kq = tid & 3;
    unsigned short o[16];
#pragma unroll
    for (int j = 0; j < 16; ++j) o[j] = f2bf(tile[kq * 16 + j][col]);
    unsigned short* dst = wt + (size_t)(m * 64 + col) * 1024 + kt * 64 + kq * 16;
    *(bf16x8*)(dst)     = *(bf16x8*)&o[0];
    *(bf16x8*)(dst + 8) = *(bf16x8*)&o[8];
  }
}

// ---------------- QKV projection via MFMA: 64-row M-tile, 8 waves -----------
// Grid 256 (1/CU). Wave (mt=wid>>2, wq=wid&3): rows mt*32+rt*16+p, cols
// wq*48+ct*16+p. W staged once per chunk feeds 64 rows -> W L2 traffic /2.
__global__ __launch_bounds__(512) void qkv_mfma_kernel(
    const float* __restrict__ x, const unsigned short* __restrict__ wt,
    unsigned short* __restrict__ qb, unsigned short* __restrict__ kb,
    unsigned short* __restrict__ vt) {
  __shared__ __align__(16) unsigned short xs[64 * 64];   // 8 KB, swizzled
  __shared__ __align__(16) unsigned short ws[192 * 64];  // 24 KB, swizzled
  const int tid  = threadIdx.x;
  const int lane = tid & 63, wid = tid >> 6;
  const int g = lane >> 4, p = lane & 15;
  const int mt = wid >> 2, wq = wid & 3;
  const size_t row0 = (size_t)blockIdx.x * 64;

  const int sr = tid >> 3, sc = tid & 7;            // x: row (0..63), 8-k group
  const float* xp = x + (row0 + sr) * EMB + sc * 8;

  f32x4 acc[2][3];
#pragma unroll
  for (int rt = 0; rt < 2; ++rt)
#pragma unroll
    for (int ct = 0; ct < 3; ++ct) acc[rt][ct] = (f32x4){0.f, 0.f, 0.f, 0.f};

  float4 rx[2];
  bf16x8 rw[3];
#pragma unroll
  for (int j = 0; j < 2; ++j) rx[j] = *(const float4*)(xp + j * 4);
#pragma unroll
  for (int it = 0; it < 3; ++it) {
    int i = tid + it * 512, col = i >> 3, cc = i & 7;
    rw[it] = *(const bf16x8*)(wt + (size_t)col * 1024 + cc * 8);
  }

  for (int kc = 0; kc < 16; ++kc) {
    __syncthreads();                       // previous chunk's reads done
#pragma unroll
    for (int j = 0; j < 2; ++j) {
      ushort4 h;
      h.x = f2bf(rx[j].x); h.y = f2bf(rx[j].y);
      h.z = f2bf(rx[j].z); h.w = f2bf(rx[j].w);
      *(ushort4*)((char*)xs + ((sr * 128 + sc * 16 + j * 8) ^ ((sr & 7) << 4))) = h;
    }
#pragma unroll
    for (int it = 0; it < 3; ++it) {
      int i = tid + it * 512, col = i >> 3, cc = i & 7;
      *(bf16x8*)((char*)ws + ((col * 128 + cc * 16) ^ ((col & 7) << 4))) = rw[it];
    }
    if (kc < 15) {                         // prefetch next chunk
      const float* xpn = xp + (kc + 1) * 64;
#pragma unroll
      for (int j = 0; j < 2; ++j) rx[j] = *(const float4*)(xpn + j * 4);
#pragma unroll
      for (int it = 0; it < 3; ++it) {
        int i = tid + it * 512, col = i >> 3, cc = i & 7;
        rw[it] = *(const bf16x8*)(wt + (size_t)col * 1024 + (kc + 1) * 64 + cc * 8);
      }
    }
    __syncthreads();
#pragma unroll
    for (int ks = 0; ks < 2; ++ks) {
      bf16x8 af[2];
#pragma unroll
      for (int rt = 0; rt < 2; ++rt) {
        int row = mt * 32 + rt * 16 + p;
        af[rt] = *(const bf16x8*)((char*)xs +
                 ((row * 128 + ks * 64 + g * 16) ^ ((row & 7) << 4)));
      }
#pragma unroll
      for (int ct = 0; ct < 3; ++ct) {
        int col = wq * 48 + ct * 16 + p;
        bf16x8 bfr = *(const bf16x8*)((char*)ws +
                     ((col * 128 + ks * 64 + g * 16) ^ ((col & 7) << 4)));
#pragma unroll
        for (int rt = 0; rt < 2; ++rt)
          acc[rt][ct] = MFMA16(af[rt], bfr, acc[rt][ct]);
      }
    }
  }

  const int b     = (int)(row0 >> 12);
  const int tbase = (int)(row0 & 4095);      // multiple of 64
  unsigned short* vtb = vt + (((size_t)b * 64 + (tbase >> 6)) * 64) * 64;
#pragma unroll
  for (int rt = 0; rt < 2; ++rt)
#pragma unroll
    for (int ct = 0; ct < 3; ++ct) {
      const int c0  = wq * 48 + ct * 16;
      const int mtx = c0 >> 6;
      const int col = (c0 & 63) + p;
#pragma unroll
      for (int r = 0; r < 4; ++r) {
        const int row = mt * 32 + rt * 16 + 4 * g + r;
        const float vf = acc[rt][ct][r];
        if (mtx == 0)      qb[(row0 + row) * HDIM + col] = f2bf(vf * 0.0450843714f);
        else if (mtx == 1) kb[(row0 + row) * HDIM + col] = f2bf(vf);
        else               vtb[(size_t)col * 64 + row]   = f2bf(vf);
      }
    }
}

// ---- one 64-key tile from swizzled LDS; cvt_pk + word-shuffle transpose ----
__device__ __forceinline__ void tile_body_lds(
    const unsigned short* __restrict__ sKb, const unsigned short* __restrict__ sVb,
    int qrel, bool diag,
    const bf16x8& qf0, const bf16x8& qf1,
    int p, int g, int cA0, int cA1, int srcA, int srcB, bool hi,
    float& m, float& l, f32x4 (&o)[4]) {
  f32x4 sc4[4];
#pragma unroll
  for (int t = 0; t < 4; ++t) {
    const int row = 16 * t + p;
    bf16x8 a0 = *(const bf16x8*)((const char*)sKb + row * 128 + cA0);
    bf16x8 a1 = *(const bf16x8*)((const char*)sKb + row * 128 + cA1);
    f32x4 a = (f32x4){0.f, 0.f, 0.f, 0.f};
    a = MFMA16(a0, qf0, a);
    a = MFMA16(a1, qf1, a);
    sc4[t] = a;
  }
  if (diag) {
#pragma unroll
    for (int t = 0; t < 4; ++t)
#pragma unroll
      for (int r = 0; r < 4; ++r)
        if (16 * t + 4 * g + r > qrel) sc4[t][r] = -1e30f;
  }
  float tm = -3e38f;
#pragma unroll
  for (int t = 0; t < 4; ++t)
#pragma unroll
    for (int r = 0; r < 4; ++r) tm = fmaxf(tm, sc4[t][r]);
  tm = fmaxf(tm, __shfl_xor(tm, 16));
  tm = fmaxf(tm, __shfl_xor(tm, 32));
  if (__any(tm > m + 11.5f)) {               // defer-max (T13)
    float mn = fmaxf(m, tm);
    float c = fexp2(m - mn);
    l *= c;
#pragma unroll
    for (int mi = 0; mi < 4; ++mi) o[mi] *= c;
    m = mn;
  }
  float psum = 0.f;
#pragma unroll
  for (int t = 0; t < 4; ++t)
#pragma unroll
    for (int r = 0; r < 4; ++r) {
      float pv = fexp2(sc4[t][r] - m);
      sc4[t][r] = pv;
      psum += pv;
    }
  l += psum;
  unsigned int pk[4][2];
#pragma unroll
  for (int t = 0; t < 4; ++t) {
    asm("v_cvt_pk_bf16_f32 %0, %1, %2"
        : "=v"(pk[t][0]) : "v"(sc4[t][0]), "v"(sc4[t][1]));
    asm("v_cvt_pk_bf16_f32 %0, %1, %2"
        : "=v"(pk[t][1]) : "v"(sc4[t][2]), "v"(sc4[t][3]));
  }
  u32x4 wb0, wb1;
#pragma unroll
  for (int h2 = 0; h2 < 2; ++h2) {
    const int src = h2 ? srcB : srcA;
    unsigned c0 = (unsigned)__shfl((int)pk[0][0], src);
    unsigned c1 = (unsigned)__shfl((int)pk[1][0], src);
    wb0[2 * h2 + 0] = hi ? c1 : c0;
    unsigned d0 = (unsigned)__shfl((int)pk[0][1], src);
    unsigned d1 = (unsigned)__shfl((int)pk[1][1], src);
    wb0[2 * h2 + 1] = hi ? d1 : d0;
    unsigned e0 = (unsigned)__shfl((int)pk[2][0], src);
    unsigned e1 = (unsigned)__shfl((int)pk[3][0], src);
    wb1[2 * h2 + 0] = hi ? e1 : e0;
    unsigned f0 = (unsigned)__shfl((int)pk[2][1], src);
    unsigned f1 = (unsigned)__shfl((int)pk[3][1], src);
    wb1[2 * h2 + 1] = hi ? f1 : f0;
  }
  bf16x8 b0 = __builtin_bit_cast(bf16x8, wb0);
  bf16x8 b1 = __builtin_bit_cast(bf16x8, wb1);
#pragma unroll
  for (int mi = 0; mi < 4; ++mi) {
    const int rowv = 16 * mi + p;
    bf16x8 va0 = *(const bf16x8*)((const char*)sVb + rowv * 128 + cA0);
    bf16x8 va1 = *(const bf16x8*)((const char*)sVb + rowv * 128 + cA1);
    o[mi] = MFMA16(va0, b0, o[mi]);
    o[mi] = MFMA16(va1, b1, o[mi]);
  }
}

__device__ __forceinline__ void item_map(int g_it, int j, int& kt, bool& isA, bool& diag) {
  if (g_it <= j) { isA = true;  kt = g_it;         diag = (g_it == j); }
  else           { isA = false; kt = g_it - j - 1; diag = (kt == 63 - j); }
}

// ---- flash attention stage 1: LDS-staged K/V, ONE barrier per item ---------
__global__ __launch_bounds__(256) void attn_partial_kernel(
    const unsigned short* __restrict__ qb, const unsigned short* __restrict__ kbm,
    const unsigned short* __restrict__ vt, float* __restrict__ pw) {
  __shared__ __align__(16) unsigned short sK[2][4096];
  __shared__ __align__(16) unsigned short sV[2][4096];
  const int tid = threadIdx.x;
  const int wid = tid >> 6, lane = tid & 63;
  const int g = lane >> 4, p = lane & 15;
  const int bid = blockIdx.x;
  const int sp = bid & 3, j = (bid >> 2) & 31, b = bid >> 7;
  const int jB = 63 - j;
  const int tq0A = j * 64 + 16 * wid;
  const int tq0B = jB * 64 + 16 * wid;

  const char* kbase = (const char*)(kbm + (size_t)b * SEQ * HDIM);
  const char* vbase = (const char*)(vt  + (size_t)b * SEQ * HDIM);

  const unsigned short* qrowA = qb + ((size_t)b * SEQ + tq0A + p) * HDIM;
  const bf16x8 qfA0 = *(const bf16x8*)(qrowA + 8 * g);
  const bf16x8 qfA1 = *(const bf16x8*)(qrowA + 32 + 8 * g);
  const unsigned short* qrowB = qb + ((size_t)b * SEQ + tq0B + p) * HDIM;
  const bf16x8 qfB0 = *(const bf16x8*)(qrowB + 8 * g);
  const bf16x8 qfB1 = *(const bf16x8*)(qrowB + 32 + 8 * g);

  const int slot0 = tid * 16, slot1 = slot0 + 4096;
  const int r0 = slot0 >> 7, koff0 = r0 * 128 + ((slot0 & 127) ^ ((r0 & 7) << 4));
  const int r1 = slot1 >> 7, koff1 = r1 * 128 + ((slot1 & 127) ^ ((r1 & 7) << 4));

  const int swz = (p & 7) << 4;
  const int cA0 = (16 * g) ^ swz, cA1 = (64 + 16 * g) ^ swz;

  const int srcA = (g & 1) * 32 + p;
  const int srcB = srcA + 16;
  const bool hi = (g >> 1) != 0;

  float mA = -1e30f, lA = 0.f, mB = -1e30f, lB = 0.f;
  f32x4 oA[4], oB[4];
#pragma unroll
  for (int mi = 0; mi < 4; ++mi) {
    oA[mi] = (f32x4){0.f, 0.f, 0.f, 0.f};
    oB[mi] = (f32x4){0.f, 0.f, 0.f, 0.f};
  }

  const int cnt = (65 - sp + NSPLIT - 1) / NSPLIT;   // 16 or 17

  bf16x8 rk0, rk1, rv0, rv1;
  {
    int kt; bool isA, diag;
    item_map(sp, j, kt, isA, diag);
    const char* kk = kbase + (size_t)kt * 8192;
    const char* vv = vbase + (size_t)kt * 8192;
    rk0 = *(const bf16x8*)(kk + koff0); rk1 = *(const bf16x8*)(kk + koff1);
    rv0 = *(const bf16x8*)(vv + koff0); rv1 = *(const bf16x8*)(vv + koff1);
  }
  *(bf16x8*)((char*)sK[0] + slot0) = rk0;
  *(bf16x8*)((char*)sK[0] + slot1) = rk1;
  *(bf16x8*)((char*)sV[0] + slot0) = rv0;
  *(bf16x8*)((char*)sV[0] + slot1) = rv1;
  if (cnt > 1) {
    int kt; bool isA, diag;
    item_map(sp + NSPLIT, j, kt, isA, diag);
    const char* kk = kbase + (size_t)kt * 8192;
    const char* vv = vbase + (size_t)kt * 8192;
    rk0 = *(const bf16x8*)(kk + koff0); rk1 = *(const bf16x8*)(kk + koff1);
    rv0 = *(const bf16x8*)(vv + koff0); rv1 = *(const bf16x8*)(vv + koff1);
  }
  __syncthreads();

  for (int ii = 0; ii < cnt; ++ii) {
    const int buf = ii & 1;
    if (ii + 1 < cnt) {
      const int nb = buf ^ 1;
      *(bf16x8*)((char*)sK[nb] + slot0) = rk0;
      *(bf16x8*)((char*)sK[nb] + slot1) = rk1;
      *(bf16x8*)((char*)sV[nb] + slot0) = rv0;
      *(bf16x8*)((char*)sV[nb] + slot1) = rv1;
    }
    if (ii + 2 < cnt) {                   // T14 issue-early
      int kt; bool isA, diag;
      item_map(sp + (ii + 2) * NSPLIT, j, kt, isA, diag);
      const char* kk = kbase + (size_t)kt * 8192;
      const char* vv = vbase + (size_t)kt * 8192;
      rk0 = *(const bf16x8*)(kk + koff0); rk1 = *(const bf16x8*)(kk + koff1);
      rv0 = *(const bf16x8*)(vv + koff0); rv1 = *(const bf16x8*)(vv + koff1);
    }
    int kt; bool isA, diag;
    item_map(sp + ii * NSPLIT, j, kt, isA, diag);
    if (isA) {
      tile_body_lds(sK[buf], sV[buf], tq0A + p - kt * 64, diag, qfA0, qfA1,
                    p, g, cA0, cA1, srcA, srcB, hi, mA, lA, oA);
    } else {
      tile_body_lds(sK[buf], sV[buf], tq0B + p - kt * 64, diag, qfB0, qfB1,
                    p, g, cA0, cA1, srcA, srcB, hi, mB, lB, oB);
    }
    __syncthreads();                      // single barrier per item
  }

  lA += __shfl_xor(lA, 16); lA += __shfl_xor(lA, 32);
  lB += __shfl_xor(lB, 16); lB += __shfl_xor(lB, 32);

  {
    const int grpA = j * 4 + wid;
    float* pp = pw + ((size_t)(b * 256 + grpA) * NSPLIT + sp) * 1056;
#pragma unroll
    for (int mi = 0; mi < 4; ++mi)
      *(f32x4*)(pp + p * 64 + 16 * mi + 4 * g) = oA[mi];
    if (g == 0) { pp[1024 + p] = mA; pp[1040 + p] = lA; }
  }
  {
    const int grpB = jB * 4 + wid;
    float* pp = pw + ((size_t)(b * 256 + grpB) * NSPLIT + sp) * 1056;
#pragma unroll
    for (int mi = 0; mi < 4; ++mi)
      *(f32x4*)(pp + p * 64 + 16 * mi + 4 * g) = oB[mi];
    if (g == 0) { pp[1024 + p] = mB; pp[1040 + p] = lB; }
  }
}

// ---- stage 2: merge NSPLIT partials per (batch, 16-query group), normalize -
__global__ __launch_bounds__(256) void attn_merge_kernel(
    const float* __restrict__ pw, float* __restrict__ out) {
  const int bid = blockIdx.x;                   // b*256 + grp
  const int b = bid >> 8, grp = bid & 255;
  const int q = threadIdx.x & 15, db = threadIdx.x >> 4;
  const float* pp = pw + (size_t)bid * NSPLIT * 1056;
  float ms[NSPLIT], ls[NSPLIT];
  float mm = -3e38f;
#pragma unroll
  for (int s = 0; s < NSPLIT; ++s) {
    ms[s] = pp[s * 1056 + 1024 + q];
    ls[s] = pp[s * 1056 + 1040 + q];
    mm = fmaxf(mm, ms[s]);
  }
  float L = 0.f, a0 = 0.f, a1 = 0.f, a2 = 0.f, a3 = 0.f;
#pragma unroll
  for (int s = 0; s < NSPLIT; ++s) {
    float sc = fexp2(ms[s] - mm);
    L += ls[s] * sc;
    float4 v = *(const float4*)(pp + s * 1056 + q * 64 + 4 * db);
    a0 += v.x * sc; a1 += v.y * sc; a2 += v.z * sc; a3 += v.w * sc;
  }
  const float inv = 1.f / L;
  float* op = out + ((size_t)b * SEQ + grp * 16 + q) * HDIM + 4 * db;
  op[0] = a0 * inv; op[1] = a1 * inv; op[2] = a2 * inv; op[3] = a3 * inv;
}

extern "C" void kernel_launch(void* const* d_in, const int* in_sizes, int n_in,
                              void* d_out, int out_size, void* d_ws, size_t ws_size,
                              hipStream_t stream) {
  const float* x  = (const float*)d_in[0];
  const float* Wq = (const float*)d_in[1];
  const float* Wk = (const float*)d_in[2];
  const float* Wv = (const float*)d_in[3];
  float* outp = (float*)d_out;

  const size_t rows = (size_t)BATCH * SEQ;        // 16384
  unsigned short* qbf = (unsigned short*)d_ws;
  unsigned short* kbf = qbf + rows * HDIM;
  unsigned short* vtb = kbf + rows * HDIM;
  unsigned short* wt  = vtb + rows * HDIM;        // 192*1024 bf16
  float* pw = (float*)(wt + 192 * 1024);          // 4096 partials x 1056 f32

  wt_kernel<<<dim3(48), dim3(256), 0, stream>>>(Wq, Wk, Wv, wt);
  qkv_mfma_kernel<<<dim3((unsigned)(rows / 64)), dim3(512), 0, stream>>>(x, wt, qbf, kbf, vtb);
  attn_partial_kernel<<<dim3(512), dim3(256), 0, stream>>>(qbf, kbf, vtb, pw);
  attn_merge_kernel<<<dim3(1024), dim3(256), 0, stream>>>(pw, outp);
}

// Round 19
// 58.001 us; speedup vs baseline: 2.9677x; 1.0172x over previous
//
#include <hip/hip_runtime.h>
#include <math.h>

#define BATCH 4
#define SEQ   4096
#define EMB   1024
#define HDIM  64
#define NSPLIT 4

typedef __attribute__((ext_vector_type(8))) short bf16x8;
typedef __attribute__((ext_vector_type(4))) float f32x4;
typedef __attribute__((ext_vector_type(4))) unsigned int u32x4;

#define MFMA16(a, b, c) __builtin_amdgcn_mfma_f32_16x16x32_bf16(a, b, c, 0, 0, 0)

__device__ __forceinline__ unsigned short f2bf(float f) {
  unsigned int u = __float_as_uint(f);
  u = (u + 0x7FFFu + ((u >> 16) & 1u)) >> 16;   // RNE
  return (unsigned short)u;
}

__device__ __forceinline__ float fexp2(float x) {  // 2^x, hw v_exp_f32
  float r;
  asm("v_exp_f32 %0, %1" : "=v"(r) : "v"(x));
  return r;
}

// ---- W pre-transpose: W[1024][64] f32 x3 -> Wt[192][1024] bf16 --------------
__global__ __launch_bounds__(256) void wt_kernel(
    const float* __restrict__ Wq, const float* __restrict__ Wk,
    const float* __restrict__ Wv, unsigned short* __restrict__ wt) {
  __shared__ float tile[64][65];
  const int bid = blockIdx.x;           // 48 = 3 matrices x 16 k-tiles
  const int m = bid >> 4, kt = bid & 15;
  const float* W = (m == 0) ? Wq : (m == 1) ? Wk : Wv;
  const int tid = threadIdx.x;
  {
    const int r = tid >> 2, c4 = tid & 3;
    const float* src = W + (size_t)(kt * 64 + r) * 64 + c4 * 16;
#pragma unroll
    for (int j = 0; j < 4; ++j) {
      float4 a = *(const float4*)(src + j * 4);
      tile[r][c4 * 16 + j * 4 + 0] = a.x;
      tile[r][c4 * 16 + j * 4 + 1] = a.y;
      tile[r][c4 * 16 + j * 4 + 2] = a.z;
      tile[r][c4 * 16 + j * 4 + 3] = a.w;
    }
  }
  __syncthreads();
  {
    const int col = tid >> 2, kq = tid & 3;
    unsigned short o[16];
#pragma unroll
    for (int j = 0; j < 16; ++j) o[j] = f2bf(tile[kq * 16 + j][col]);
    unsigned short* dst = wt + (size_t)(m * 64 + col) * 1024 + kt * 64 + kq * 16;
    *(bf16x8*)(dst)     = *(bf16x8*)&o[0];
    *(bf16x8*)(dst + 8) = *(bf16x8*)&o[8];
  }
}

// ---------------- QKV projection via MFMA: 64-row M-tile, 8 waves (r18) -----
__global__ __launch_bounds__(512) void qkv_mfma_kernel(
    const float* __restrict__ x, const unsigned short* __restrict__ wt,
    unsigned short* __restrict__ qb, unsigned short* __restrict__ kb,
    unsigned short* __restrict__ vt) {
  __shared__ __align__(16) unsigned short xs[64 * 64];
  __shared__ __align__(16) unsigned short ws[192 * 64];
  const int tid  = threadIdx.x;
  const int lane = tid & 63, wid = tid >> 6;
  const int g = lane >> 4, p = lane & 15;
  const int mt = wid >> 2, wq = wid & 3;
  const size_t row0 = (size_t)blockIdx.x * 64;

  const int sr = tid >> 3, sc = tid & 7;
  const float* xp = x + (row0 + sr) * EMB + sc * 8;

  f32x4 acc[2][3];
#pragma unroll
  for (int rt = 0; rt < 2; ++rt)
#pragma unroll
    for (int ct = 0; ct < 3; ++ct) acc[rt][ct] = (f32x4){0.f, 0.f, 0.f, 0.f};

  float4 rx[2];
  bf16x8 rw[3];
#pragma unroll
  for (int j = 0; j < 2; ++j) rx[j] = *(const float4*)(xp + j * 4);
#pragma unroll
  for (int it = 0; it < 3; ++it) {
    int i = tid + it * 512, col = i >> 3, cc = i & 7;
    rw[it] = *(const bf16x8*)(wt + (size_t)col * 1024 + cc * 8);
  }

  for (int kc = 0; kc < 16; ++kc) {
    __syncthreads();
#pragma unroll
    for (int j = 0; j < 2; ++j) {
      ushort4 h;
      h.x = f2bf(rx[j].x); h.y = f2bf(rx[j].y);
      h.z = f2bf(rx[j].z); h.w = f2bf(rx[j].w);
      *(ushort4*)((char*)xs + ((sr * 128 + sc * 16 + j * 8) ^ ((sr & 7) << 4))) = h;
    }
#pragma unroll
    for (int it = 0; it < 3; ++it) {
      int i = tid + it * 512, col = i >> 3, cc = i & 7;
      *(bf16x8*)((char*)ws + ((col * 128 + cc * 16) ^ ((col & 7) << 4))) = rw[it];
    }
    if (kc < 15) {
      const float* xpn = xp + (kc + 1) * 64;
#pragma unroll
      for (int j = 0; j < 2; ++j) rx[j] = *(const float4*)(xpn + j * 4);
#pragma unroll
      for (int it = 0; it < 3; ++it) {
        int i = tid + it * 512, col = i >> 3, cc = i & 7;
        rw[it] = *(const bf16x8*)(wt + (size_t)col * 1024 + (kc + 1) * 64 + cc * 8);
      }
    }
    __syncthreads();
#pragma unroll
    for (int ks = 0; ks < 2; ++ks) {
      bf16x8 af[2];
#pragma unroll
      for (int rt = 0; rt < 2; ++rt) {
        int row = mt * 32 + rt * 16 + p;
        af[rt] = *(const bf16x8*)((char*)xs +
                 ((row * 128 + ks * 64 + g * 16) ^ ((row & 7) << 4)));
      }
#pragma unroll
      for (int ct = 0; ct < 3; ++ct) {
        int col = wq * 48 + ct * 16 + p;
        bf16x8 bfr = *(const bf16x8*)((char*)ws +
                     ((col * 128 + ks * 64 + g * 16) ^ ((col & 7) << 4)));
#pragma unroll
        for (int rt = 0; rt < 2; ++rt)
          acc[rt][ct] = MFMA16(af[rt], bfr, acc[rt][ct]);
      }
    }
  }

  const int b     = (int)(row0 >> 12);
  const int tbase = (int)(row0 & 4095);
  unsigned short* vtb = vt + (((size_t)b * 64 + (tbase >> 6)) * 64) * 64;
#pragma unroll
  for (int rt = 0; rt < 2; ++rt)
#pragma unroll
    for (int ct = 0; ct < 3; ++ct) {
      const int c0  = wq * 48 + ct * 16;
      const int mtx = c0 >> 6;
      const int col = (c0 & 63) + p;
#pragma unroll
      for (int r = 0; r < 4; ++r) {
        const int row = mt * 32 + rt * 16 + 4 * g + r;
        const float vf = acc[rt][ct][r];
        if (mtx == 0)      qb[(row0 + row) * HDIM + col] = f2bf(vf * 0.0450843714f);
        else if (mtx == 1) kb[(row0 + row) * HDIM + col] = f2bf(vf);
        else               vtb[(size_t)col * 64 + row]   = f2bf(vf);
      }
    }
}

// ---- one 64-key tile from swizzled LDS; cvt_pk + word-shuffle transpose ----
__device__ __forceinline__ void tile_body_lds(
    const unsigned short* __restrict__ sKb, const unsigned short* __restrict__ sVb,
    int qrel, bool diag,
    const bf16x8& qf0, const bf16x8& qf1,
    int p, int g, int cA0, int cA1, int srcA, int srcB, bool hi,
    float& m, float& l, f32x4 (&o)[4]) {
  f32x4 sc4[4];
#pragma unroll
  for (int t = 0; t < 4; ++t) {
    const int row = 16 * t + p;
    bf16x8 a0 = *(const bf16x8*)((const char*)sKb + row * 128 + cA0);
    bf16x8 a1 = *(const bf16x8*)((const char*)sKb + row * 128 + cA1);
    f32x4 a = (f32x4){0.f, 0.f, 0.f, 0.f};
    a = MFMA16(a0, qf0, a);
    a = MFMA16(a1, qf1, a);
    sc4[t] = a;
  }
  if (diag) {
#pragma unroll
    for (int t = 0; t < 4; ++t)
#pragma unroll
      for (int r = 0; r < 4; ++r)
        if (16 * t + 4 * g + r > qrel) sc4[t][r] = -1e30f;
  }
  float tm = -3e38f;
#pragma unroll
  for (int t = 0; t < 4; ++t)
#pragma unroll
    for (int r = 0; r < 4; ++r) tm = fmaxf(tm, sc4[t][r]);
  tm = fmaxf(tm, __shfl_xor(tm, 16));
  tm = fmaxf(tm, __shfl_xor(tm, 32));
  if (__any(tm > m + 11.5f)) {               // defer-max (T13)
    float mn = fmaxf(m, tm);
    float c = fexp2(m - mn);
    l *= c;
#pragma unroll
    for (int mi = 0; mi < 4; ++mi) o[mi] *= c;
    m = mn;
  }
  float psum = 0.f;
#pragma unroll
  for (int t = 0; t < 4; ++t)
#pragma unroll
    for (int r = 0; r < 4; ++r) {
      float pv = fexp2(sc4[t][r] - m);
      sc4[t][r] = pv;
      psum += pv;
    }
  l += psum;
  unsigned int pk[4][2];
#pragma unroll
  for (int t = 0; t < 4; ++t) {
    asm("v_cvt_pk_bf16_f32 %0, %1, %2"
        : "=v"(pk[t][0]) : "v"(sc4[t][0]), "v"(sc4[t][1]));
    asm("v_cvt_pk_bf16_f32 %0, %1, %2"
        : "=v"(pk[t][1]) : "v"(sc4[t][2]), "v"(sc4[t][3]));
  }
  u32x4 wb0, wb1;
#pragma unroll
  for (int h2 = 0; h2 < 2; ++h2) {
    const int src = h2 ? srcB : srcA;
    unsigned c0 = (unsigned)__shfl((int)pk[0][0], src);
    unsigned c1 = (unsigned)__shfl((int)pk[1][0], src);
    wb0[2 * h2 + 0] = hi ? c1 : c0;
    unsigned d0 = (unsigned)__shfl((int)pk[0][1], src);
    unsigned d1 = (unsigned)__shfl((int)pk[1][1], src);
    wb0[2 * h2 + 1] = hi ? d1 : d0;
    unsigned e0 = (unsigned)__shfl((int)pk[2][0], src);
    unsigned e1 = (unsigned)__shfl((int)pk[3][0], src);
    wb1[2 * h2 + 0] = hi ? e1 : e0;
    unsigned f0 = (unsigned)__shfl((int)pk[2][1], src);
    unsigned f1 = (unsigned)__shfl((int)pk[3][1], src);
    wb1[2 * h2 + 1] = hi ? f1 : f0;
  }
  bf16x8 b0 = __builtin_bit_cast(bf16x8, wb0);
  bf16x8 b1 = __builtin_bit_cast(bf16x8, wb1);
#pragma unroll
  for (int mi = 0; mi < 4; ++mi) {
    const int rowv = 16 * mi + p;
    bf16x8 va0 = *(const bf16x8*)((const char*)sVb + rowv * 128 + cA0);
    bf16x8 va1 = *(const bf16x8*)((const char*)sVb + rowv * 128 + cA1);
    o[mi] = MFMA16(va0, b0, o[mi]);
    o[mi] = MFMA16(va1, b1, o[mi]);
  }
}

// pair (j, 31-j) of 128-row q-blocks; nA=2j+2, nB=64-2j, 66 items total.
// Last TWO tiles of each side carry the causal mask (qrel handles per-lane).
__device__ __forceinline__ void item_map128(int g_it, int nA, int nB,
                                            int& kt, bool& isA, bool& diag) {
  if (g_it < nA) { isA = true;  kt = g_it;      diag = (kt >= nA - 2); }
  else           { isA = false; kt = g_it - nA; diag = (kt >= nB - 2); }
}

// ---- flash attention stage 1: 128-row Q pairs, K/V shared by 8 waves -------
// Block (b, j, sp): pair A = 128-row q-block j, B = block 31-j; items sp,
// sp+4,... of the 66-item list. Each staged 16KB tile feeds 256 queries ->
// K/V L2 traffic 69MB (was 133MB). Grid 256 x 512thr = 8 waves/CU.
__global__ __launch_bounds__(512) void attn_partial_kernel(
    const unsigned short* __restrict__ qb, const unsigned short* __restrict__ kbm,
    const unsigned short* __restrict__ vt, float* __restrict__ pw) {
  __shared__ __align__(16) unsigned short sK[2][4096];
  __shared__ __align__(16) unsigned short sV[2][4096];
  const int tid = threadIdx.x;
  const int wid = tid >> 6, lane = tid & 63;     // wid 0..7
  const int g = lane >> 4, p = lane & 15;
  const int bid = blockIdx.x;
  const int sp = bid & 3, j = (bid >> 2) & 15, b = bid >> 6;
  const int jB = 31 - j;
  const int nA = 2 * j + 2, nB = 64 - 2 * j;     // nA+nB == 66
  const int tq0A = j * 128 + 16 * wid;
  const int tq0B = jB * 128 + 16 * wid;

  const char* kbase = (const char*)(kbm + (size_t)b * SEQ * HDIM);
  const char* vbase = (const char*)(vt  + (size_t)b * SEQ * HDIM);

  const unsigned short* qrowA = qb + ((size_t)b * SEQ + tq0A + p) * HDIM;
  const bf16x8 qfA0 = *(const bf16x8*)(qrowA + 8 * g);
  const bf16x8 qfA1 = *(const bf16x8*)(qrowA + 32 + 8 * g);
  const unsigned short* qrowB = qb + ((size_t)b * SEQ + tq0B + p) * HDIM;
  const bf16x8 qfB0 = *(const bf16x8*)(qrowB + 8 * g);
  const bf16x8 qfB1 = *(const bf16x8*)(qrowB + 32 + 8 * g);

  // staging: 512 threads x one 16B slot each for K and V (8KB per array)
  const int slot = tid * 16;
  const int r0 = slot >> 7, koff = r0 * 128 + ((slot & 127) ^ ((r0 & 7) << 4));

  const int swz = (p & 7) << 4;
  const int cA0 = (16 * g) ^ swz, cA1 = (64 + 16 * g) ^ swz;

  const int srcA = (g & 1) * 32 + p;
  const int srcB = srcA + 16;
  const bool hi = (g >> 1) != 0;

  float mA = -1e30f, lA = 0.f, mB = -1e30f, lB = 0.f;
  f32x4 oA[4], oB[4];
#pragma unroll
  for (int mi = 0; mi < 4; ++mi) {
    oA[mi] = (f32x4){0.f, 0.f, 0.f, 0.f};
    oB[mi] = (f32x4){0.f, 0.f, 0.f, 0.f};
  }

  const int cnt = (66 - sp + NSPLIT - 1) / NSPLIT;   // 16 or 17

  bf16x8 rk0, rv0;
  // prologue: load item 0, write buf0, preload item 1
  {
    int kt; bool isA, diag;
    item_map128(sp, nA, nB, kt, isA, diag);
    rk0 = *(const bf16x8*)(kbase + (size_t)kt * 8192 + koff);
    rv0 = *(const bf16x8*)(vbase + (size_t)kt * 8192 + koff);
  }
  *(bf16x8*)((char*)sK[0] + slot) = rk0;
  *(bf16x8*)((char*)sV[0] + slot) = rv0;
  if (cnt > 1) {
    int kt; bool isA, diag;
    item_map128(sp + NSPLIT, nA, nB, kt, isA, diag);
    rk0 = *(const bf16x8*)(kbase + (size_t)kt * 8192 + koff);
    rv0 = *(const bf16x8*)(vbase + (size_t)kt * 8192 + koff);
  }
  __syncthreads();

  for (int ii = 0; ii < cnt; ++ii) {
    const int buf = ii & 1;
    if (ii + 1 < cnt) {                   // write item ii+1 into other buf
      const int nb = buf ^ 1;
      *(bf16x8*)((char*)sK[nb] + slot) = rk0;
      *(bf16x8*)((char*)sV[nb] + slot) = rv0;
    }
    if (ii + 2 < cnt) {                   // T14 issue-early: load item ii+2
      int kt; bool isA, diag;
      item_map128(sp + (ii + 2) * NSPLIT, nA, nB, kt, isA, diag);
      rk0 = *(const bf16x8*)(kbase + (size_t)kt * 8192 + koff);
      rv0 = *(const bf16x8*)(vbase + (size_t)kt * 8192 + koff);
    }
    int kt; bool isA, diag;
    item_map128(sp + ii * NSPLIT, nA, nB, kt, isA, diag);
    if (isA) {
      tile_body_lds(sK[buf], sV[buf], tq0A + p - kt * 64, diag, qfA0, qfA1,
                    p, g, cA0, cA1, srcA, srcB, hi, mA, lA, oA);
    } else {
      tile_body_lds(sK[buf], sV[buf], tq0B + p - kt * 64, diag, qfB0, qfB1,
                    p, g, cA0, cA1, srcA, srcB, hi, mB, lB, oB);
    }
    __syncthreads();                      // single barrier per item
  }

  lA += __shfl_xor(lA, 16); lA += __shfl_xor(lA, 32);
  lB += __shfl_xor(lB, 16); lB += __shfl_xor(lB, 32);

  {
    const int grpA = j * 8 + wid;                    // 0..127
    float* pp = pw + ((size_t)(b * 256 + grpA) * NSPLIT + sp) * 1056;
#pragma unroll
    for (int mi = 0; mi < 4; ++mi)
      *(f32x4*)(pp + p * 64 + 16 * mi + 4 * g) = oA[mi];
    if (g == 0) { pp[1024 + p] = mA; pp[1040 + p] = lA; }
  }
  {
    const int grpB = jB * 8 + wid;                   // 128..255
    float* pp = pw + ((size_t)(b * 256 + grpB) * NSPLIT + sp) * 1056;
#pragma unroll
    for (int mi = 0; mi < 4; ++mi)
      *(f32x4*)(pp + p * 64 + 16 * mi + 4 * g) = oB[mi];
    if (g == 0) { pp[1024 + p] = mB; pp[1040 + p] = lB; }
  }
}

// ---- stage 2: merge NSPLIT partials per (batch, 16-query group), normalize -
__global__ __launch_bounds__(256) void attn_merge_kernel(
    const float* __restrict__ pw, float* __restrict__ out) {
  const int bid = blockIdx.x;                   // b*256 + grp
  const int b = bid >> 8, grp = bid & 255;
  const int q = threadIdx.x & 15, db = threadIdx.x >> 4;
  const float* pp = pw + (size_t)bid * NSPLIT * 1056;
  float ms[NSPLIT], ls[NSPLIT];
  float mm = -3e38f;
#pragma unroll
  for (int s = 0; s < NSPLIT; ++s) {
    ms[s] = pp[s * 1056 + 1024 + q];
    ls[s] = pp[s * 1056 + 1040 + q];
    mm = fmaxf(mm, ms[s]);
  }
  float L = 0.f, a0 = 0.f, a1 = 0.f, a2 = 0.f, a3 = 0.f;
#pragma unroll
  for (int s = 0; s < NSPLIT; ++s) {
    float sc = fexp2(ms[s] - mm);
    L += ls[s] * sc;
    float4 v = *(const float4*)(pp + s * 1056 + q * 64 + 4 * db);
    a0 += v.x * sc; a1 += v.y * sc; a2 += v.z * sc; a3 += v.w * sc;
  }
  const float inv = 1.f / L;
  float* op = out + ((size_t)b * SEQ + grp * 16 + q) * HDIM + 4 * db;
  op[0] = a0 * inv; op[1] = a1 * inv; op[2] = a2 * inv; op[3] = a3 * inv;
}

extern "C" void kernel_launch(void* const* d_in, const int* in_sizes, int n_in,
                              void* d_out, int out_size, void* d_ws, size_t ws_size,
                              hipStream_t stream) {
  const float* x  = (const float*)d_in[0];
  const float* Wq = (const float*)d_in[1];
  const float* Wk = (const float*)d_in[2];
  const float* Wv = (const float*)d_in[3];
  float* outp = (float*)d_out;

  const size_t rows = (size_t)BATCH * SEQ;        // 16384
  unsigned short* qbf = (unsigned short*)d_ws;
  unsigned short* kbf = qbf + rows * HDIM;
  unsigned short* vtb = kbf + rows * HDIM;
  unsigned short* wt  = vtb + rows * HDIM;        // 192*1024 bf16
  float* pw = (float*)(wt + 192 * 1024);          // 4096 partials x 1056 f32

  wt_kernel<<<dim3(48), dim3(256), 0, stream>>>(Wq, Wk, Wv, wt);
  qkv_mfma_kernel<<<dim3((unsigned)(rows / 64)), dim3(512), 0, stream>>>(x, wt, qbf, kbf, vtb);
  attn_partial_kernel<<<dim3(256), dim3(512), 0, stream>>>(qbf, kbf, vtb, pw);
  attn_merge_kernel<<<dim3(1024), dim3(256), 0, stream>>>(pw, outp);
}